// Round 8
// baseline (342.012 us; speedup 1.0000x reference)
//
#include <hip/hip_runtime.h>
#include <math.h>

// Problem constants (fixed by reference)
static constexpr int NN = 50000;   // nodes
static constexpr int EE = 400000;  // edges (without self loops)
static constexpr int GG = 2048;    // graphs
static constexpr int TASKS = 12;

typedef __attribute__((ext_vector_type(8))) short short8;   // 8 bf16 (4 VGPRs)
typedef __attribute__((ext_vector_type(4))) float floatx4;  // MFMA acc

__device__ __forceinline__ unsigned short f2bf(float f) {
  unsigned u = __float_as_uint(f);
  u = u + 0x7fffu + ((u >> 16) & 1u);  // RNE
  return (unsigned short)(u >> 16);
}
__device__ __forceinline__ float bflo(unsigned u) { return __uint_as_float(u << 16); }
__device__ __forceinline__ float bfhi(unsigned u) { return __uint_as_float(u & 0xffff0000u); }

// ---------------------------------------------------------------------------
// Fused independent preamble, grid-partitioned:
//   [0,NBDEG)       in-degree histogram (distributed atomics — safe)
//   [+NBMEAN)       edge_attr mean sums (LDS pre-reduce, 6 atomics/blk — R5 lesson)
//   [+NBX)          x -> bf16 [NN][32] zero-padded (8 outputs/thread)
//   [+NW1)          W1 -> bf16^T [256][32]
//   [+NW2)          W2 -> bf16^T [256][256]
static constexpr int NBDEG = (EE + 255) / 256;     // 1563
static constexpr int NBMEAN = 256;
static constexpr int NBX = (NN * 4 + 255) / 256;   // 782 (thread = 8 bf16 outs)
static constexpr int NW1 = 32;
static constexpr int NW2 = 256;
__global__ void k_pre(const int* __restrict__ dst, const float* __restrict__ ea,
                      const float* __restrict__ x, const float* __restrict__ W1,
                      const float* __restrict__ W2, int* __restrict__ deg,
                      float* __restrict__ msum, unsigned short* __restrict__ xb,
                      unsigned short* __restrict__ w1t, unsigned short* __restrict__ w2t) {
  const int b = blockIdx.x;
  const int t = threadIdx.x;
  if (b < NBDEG) {
    int e = b * 256 + t;
    if (e < EE) atomicAdd(&deg[dst[e]], 1);
  } else if (b < NBDEG + NBMEAN) {
    float s[6] = {0, 0, 0, 0, 0, 0};
    for (int e = (b - NBDEG) * 256 + t; e < EE; e += NBMEAN * 256) {
#pragma unroll
      for (int d = 0; d < 6; d++) s[d] += ea[(size_t)e * 6 + d];
    }
    __shared__ float ls[6];
    if (t < 6) ls[t] = 0.f;
    __syncthreads();
#pragma unroll
    for (int d = 0; d < 6; d++) atomicAdd(&ls[d], s[d]);
    __syncthreads();
    if (t < 6) atomicAdd(&msum[t], ls[t]);
  } else if (b < NBDEG + NBMEAN + NBX) {
    int i = (b - NBDEG - NBMEAN) * 256 + t;  // i indexes 8-element chunks
    if (i < NN * 4) {
      int n = i >> 2, seg = i & 3;
      unsigned short v[8];
#pragma unroll
      for (int j = 0; j < 8; j++) {
        int k = seg * 8 + j;
        v[j] = (k < 29) ? f2bf(x[(size_t)n * 29 + k]) : (unsigned short)0;
      }
      *(short8*)(xb + (size_t)n * 32 + seg * 8) = *(short8*)v;
    }
  } else if (b < NBDEG + NBMEAN + NBX + NW1) {
    int i = (b - NBDEG - NBMEAN - NBX) * 256 + t;
    int n = i >> 5, k = i & 31;
    w1t[i] = (k < 29) ? f2bf(W1[(size_t)k * 256 + n]) : (unsigned short)0;
  } else {
    int i = (b - NBDEG - NBMEAN - NBX - NW1) * 256 + t;
    int n = i >> 8, k = i & 255;
    w2t[i] = f2bf(W2[(size_t)k * 256 + n]);
  }
}

// block-level exclusive scan of deg -> rowptr (partial), block totals -> bsums
__global__ void k_scan1(const int* __restrict__ deg, int* __restrict__ rowptr, int* __restrict__ bsums) {
  __shared__ int sh[256];
  int i = blockIdx.x * 256 + threadIdx.x;
  int v = (i < NN) ? deg[i] : 0;
  sh[threadIdx.x] = v;
  __syncthreads();
  for (int off = 1; off < 256; off <<= 1) {
    int t = (threadIdx.x >= off) ? sh[threadIdx.x - off] : 0;
    __syncthreads();
    sh[threadIdx.x] += t;
    __syncthreads();
  }
  if (i < NN) rowptr[i] = sh[threadIdx.x] - v;  // exclusive within block
  if (threadIdx.x == 255) bsums[blockIdx.x] = sh[255];
}

// fused scan2+scan3: every block redundantly scans the 196 block sums,
// then applies its own block's exclusive prefix to rowptr.
__global__ void k_scan23(int* __restrict__ rowptr, const int* __restrict__ bsums, int nb) {
  __shared__ int sh[256];
  const int t = threadIdx.x;
  sh[t] = (t < nb) ? bsums[t] : 0;
  __syncthreads();
  for (int off = 1; off < 256; off <<= 1) {
    int tv = (t >= off) ? sh[t - off] : 0;
    __syncthreads();
    sh[t] += tv;  // inclusive scan
    __syncthreads();
  }
  const int add = (blockIdx.x == 0) ? 0 : sh[blockIdx.x - 1];
  int i = blockIdx.x * 256 + t;
  if (i < NN) rowptr[i] += add;
  if (i == 0) rowptr[NN] = EE;
}

// scatter edges into CSR-by-dst (+ per-layer params in 2 trailing blocks)
__global__ void k_scatparams(const int* __restrict__ ei, const int* __restrict__ rowptr,
                             int* __restrict__ cursor, int* __restrict__ csrc,
                             int* __restrict__ eslot, const float* __restrict__ We1,
                             const float* __restrict__ ae1, const float* __restrict__ We2,
                             const float* __restrict__ ae2, const float* __restrict__ msum,
                             float* __restrict__ p1, float* __restrict__ p2) {
  const int b = blockIdx.x;
  const int t = threadIdx.x;
  if (b < NBDEG) {
    int e = b * 256 + t;
    if (e >= EE) return;
    int s = ei[e];
    int d = ei[EE + e];
    int p = atomicAdd(&cursor[d], 1);
    int slot = rowptr[d] + p;
    csrc[slot] = s;
    eslot[e] = slot;
  } else {
    const int layer = b - NBDEG;
    const float* We = layer ? We2 : We1;
    const float* ae = layer ? ae2 : ae1;
    float* params = layer ? p2 : p1;
    __shared__ float vsh[24];
    if (t < 24) {
      int d = t >> 2, h = t & 3;
      float s = 0.f;
      for (int c = 0; c < 64; c++) s += We[d * 256 + h * 64 + c] * ae[h * 64 + c];
      vsh[t] = s;
      params[t] = s;
    }
    __syncthreads();
    if (t < 4) {
      float s = 0.f;
      const float invE = 1.0f / (float)EE;
#pragma unroll
      for (int d = 0; d < 6; d++) s += (msum[d] * invE) * vsh[d * 4 + t];
      params[24 + t] = s;
    }
  }
}

// LDS-free bf16 MFMA GEMM: Y[M,256](bf16) = A[M,Kp] @ Bt[256,Kp] (both bf16, B^T).
// BM=128, BN=256, BK=32; 4 waves; wave w owns cols [64w,64w+64) = head w.
// A/B fragments loaded straight from global (all tiles L2-resident; R7 showed the
// LDS-staged version was barrier+bank-conflict bound: MfmaUtil 5%, 1e6 conflicts).
// No __syncthreads anywhere. Fused per-head logits als/ald in the epilogue.
__global__ __launch_bounds__(256) void k_gemm_mfma(
    const unsigned short* __restrict__ A, const unsigned short* __restrict__ Bt,
    const float* __restrict__ a_s, const float* __restrict__ a_d,
    unsigned short* __restrict__ Y, float* __restrict__ als, float* __restrict__ ald,
    int M, int Kp) {
  const int tid = threadIdx.x;
  const int lane = tid & 63;
  const int w = tid >> 6;
  const int l15 = lane & 15;
  const int quad = lane >> 4;
  const int row0 = blockIdx.x * 128;

  floatx4 acc[8][4];
#pragma unroll
  for (int i = 0; i < 8; i++)
#pragma unroll
    for (int j = 0; j < 4; j++) acc[i][j] = {0.f, 0.f, 0.f, 0.f};

  // per-lane source pointers (advance 32 shorts per phase)
  const unsigned short* pa[8];
  const unsigned short* pb[4];
#pragma unroll
  for (int i = 0; i < 8; i++) {
    int r = row0 + i * 16 + l15;
    if (r >= M) r = M - 1;  // clamp: harmless read, stores guarded below
    pa[i] = A + (size_t)r * Kp + quad * 8;
  }
#pragma unroll
  for (int j = 0; j < 4; j++) pb[j] = Bt + (size_t)(w * 64 + j * 16 + l15) * Kp + quad * 8;

  for (int k0 = 0; k0 < Kp; k0 += 32) {
    short8 af[8], bfr[4];
#pragma unroll
    for (int i = 0; i < 8; i++) af[i] = *(const short8*)pa[i];
#pragma unroll
    for (int j = 0; j < 4; j++) bfr[j] = *(const short8*)pb[j];
#pragma unroll
    for (int i = 0; i < 8; i++) pa[i] += 32;
#pragma unroll
    for (int j = 0; j < 4; j++) pb[j] += 32;
#pragma unroll
    for (int i = 0; i < 8; i++)
#pragma unroll
      for (int j = 0; j < 4; j++)
        acc[i][j] = __builtin_amdgcn_mfma_f32_16x16x32_bf16(af[i], bfr[j], acc[i][j], 0, 0, 0);
  }
  // epilogue: C/D layout (m89) col = lane&15, row = (lane>>4)*4 + reg.
  // Wave w's cols w*64+j*16+l15 are exactly head w -> per-head dot reduces in-wave.
  float asc[4], adc[4];
#pragma unroll
  for (int j = 0; j < 4; j++) {
    asc[j] = a_s[w * 64 + j * 16 + l15];
    adc[j] = a_d[w * 64 + j * 16 + l15];
  }
#pragma unroll
  for (int i = 0; i < 8; i++) {
#pragma unroll
    for (int r = 0; r < 4; r++) {
      const int row = row0 + i * 16 + quad * 4 + r;
      unsigned ub[4];
      float hv[4];
#pragma unroll
      for (int j = 0; j < 4; j++) {
        ub[j] = f2bf(acc[i][j][r]);
        hv[j] = __uint_as_float(ub[j] << 16);  // dot uses the rounded value (matches agg reads)
      }
      if (row < M) {
#pragma unroll
        for (int j = 0; j < 4; j++) Y[(size_t)row * 256 + w * 64 + j * 16 + l15] = (unsigned short)ub[j];
      }
      float ps = hv[0] * asc[0] + hv[1] * asc[1] + hv[2] * asc[2] + hv[3] * asc[3];
      float pd = hv[0] * adc[0] + hv[1] * adc[1] + hv[2] * adc[2] + hv[3] * adc[3];
#pragma unroll
      for (int off = 1; off < 16; off <<= 1) {
        ps += __shfl_xor(ps, off, 64);
        pd += __shfl_xor(pd, off, 64);
      }
      if (l15 == 0 && row < M) {
        als[row * 4 + w] = ps;
        ald[row * 4 + w] = pd;
      }
    }
  }
}

__device__ __forceinline__ float leaky02(float x) { return x > 0.f ? x : 0.2f * x; }

// per-edge exp(leaky(logit)) written in CSR slot order.
// Logits are O(1) (0.1-scaled weights) so no max-subtraction needed; exp can't overflow.
__global__ void k_edge(const int* __restrict__ ei, const float* __restrict__ ea,
                       const float* __restrict__ als, const float* __restrict__ ald,
                       const int* __restrict__ eslot, const float* __restrict__ params,
                       float* __restrict__ exa) {
  int e = blockIdx.x * blockDim.x + threadIdx.x;
  if (e >= EE) return;
  int src = ei[e], dst = ei[EE + e];
  float4 s4 = *(const float4*)(als + (size_t)src * 4);
  float4 d4 = *(const float4*)(ald + (size_t)dst * 4);
  float ed[6];
#pragma unroll
  for (int d = 0; d < 6; d++) ed[d] = ea[(size_t)e * 6 + d];
  float sl[4] = {s4.x + d4.x, s4.y + d4.y, s4.z + d4.z, s4.w + d4.w};
  float out[4];
#pragma unroll
  for (int h = 0; h < 4; h++) {
    float x = sl[h];
#pragma unroll
    for (int d = 0; d < 6; d++) x += ed[d] * params[d * 4 + h];
    out[h] = __expf(leaky02(x));
  }
  *(float4*)(exa + (size_t)eslot[e] * 4) = make_float4(out[0], out[1], out[2], out[3]);
}

// GAT aggregation on bf16 h, one wave per node, TWO edges in flight per iteration:
// lanes 0-31 process even CSR slots, 32-63 odd. Lane covers 8 channels (16B load),
// head = sl>>3 so each lane needs exactly one softmax weight per edge.
// out = (Σ ex·h[src] + ex_self·h[n]) / Σ ex, +b, relu -> bf16.
__global__ __launch_bounds__(256) void k_agg(
    const unsigned short* __restrict__ hinb, const float* __restrict__ als,
    const float* __restrict__ ald, const int* __restrict__ rowptr, const int* __restrict__ csrc,
    const float* __restrict__ exa, const float* __restrict__ params, const float* __restrict__ bias,
    unsigned short* __restrict__ houtb) {
  const int lane = threadIdx.x & 63;
  const int n = blockIdx.x * 4 + (threadIdx.x >> 6);
  if (n >= NN) return;
  const int half = lane >> 5;  // 0: even slots, 1: odd slots
  const int sl = lane & 31;    // 16B chunk (8 channels) within row
  const int head = sl >> 3;

  float acc[8];
  float ssum;
  {
    float slg = leaky02(als[n * 4 + head] + ald[n * 4 + head] + params[24 + head]);
    float exs = __expf(slg);
    float wgt = (half == 0) ? exs : 0.f;  // self term counted once (cross-half merge later)
    ssum = wgt;
    uint4 uv = *(const uint4*)(hinb + (size_t)n * 256 + sl * 8);
    acc[0] = bflo(uv.x) * wgt;
    acc[1] = bfhi(uv.x) * wgt;
    acc[2] = bflo(uv.y) * wgt;
    acc[3] = bfhi(uv.y) * wgt;
    acc[4] = bflo(uv.z) * wgt;
    acc[5] = bfhi(uv.z) * wgt;
    acc[6] = bflo(uv.w) * wgt;
    acc[7] = bfhi(uv.w) * wgt;
  }
  const int end = rowptr[n + 1];
  int s = rowptr[n] + half;
  int sn = 0;
  float ex = 0.f;
  if (s < end) {
    sn = csrc[s];
    ex = exa[(size_t)s * 4 + head];
  }
  while (s < end) {
    const int sc = sn;
    const float exc = ex;
    const int s2 = s + 2;
    if (s2 < end) {  // prefetch next slot's metadata
      sn = csrc[s2];
      ex = exa[(size_t)s2 * 4 + head];
    }
    uint4 uv = *(const uint4*)(hinb + (size_t)sc * 256 + sl * 8);
    acc[0] += bflo(uv.x) * exc;
    acc[1] += bfhi(uv.x) * exc;
    acc[2] += bflo(uv.y) * exc;
    acc[3] += bfhi(uv.y) * exc;
    acc[4] += bflo(uv.z) * exc;
    acc[5] += bfhi(uv.z) * exc;
    acc[6] += bflo(uv.w) * exc;
    acc[7] += bfhi(uv.w) * exc;
    ssum += exc;
    s = s2;
  }
  // merge even/odd halves (same channel set lives at lane and lane^32)
#pragma unroll
  for (int j = 0; j < 8; j++) acc[j] += __shfl_xor(acc[j], 32, 64);
  ssum += __shfl_xor(ssum, 32, 64);
  if (half == 0) {
    const float inv = 1.f / (ssum + 1e-16f);
    float4 b0 = *(const float4*)(bias + sl * 8);
    float4 b1 = *(const float4*)(bias + sl * 8 + 4);
    const float bb[8] = {b0.x, b0.y, b0.z, b0.w, b1.x, b1.y, b1.z, b1.w};
    uint p[4];
#pragma unroll
    for (int j = 0; j < 4; j++) {
      float e0 = fmaxf(acc[2 * j] * inv + bb[2 * j], 0.f);
      float e1 = fmaxf(acc[2 * j + 1] * inv + bb[2 * j + 1], 0.f);
      p[j] = (uint)f2bf(e0) | ((uint)f2bf(e1) << 16);
    }
    *(uint4*)(houtb + (size_t)n * 256 + sl * 8) = make_uint4(p[0], p[1], p[2], p[3]);
  }
}

// per-graph mean pool (bf16 in) + readout linear (256->12)
__global__ __launch_bounds__(256) void k_pool(const unsigned short* __restrict__ hb,
                                              const int* __restrict__ batch,
                                              const float* __restrict__ Wl,
                                              const float* __restrict__ bl,
                                              float* __restrict__ out) {
  int g = blockIdx.x;
  int t = threadIdx.x;
  int lo = 0, hi = NN;
  while (lo < hi) {
    int mid = (lo + hi) >> 1;
    if (batch[mid] < g) lo = mid + 1; else hi = mid;
  }
  int start = lo;
  hi = NN;
  while (lo < hi) {
    int mid = (lo + hi) >> 1;
    if (batch[mid] < g + 1) lo = mid + 1; else hi = mid;
  }
  int end = lo;
  __shared__ float sp[256];
  if (t < 128) {
    float s0 = 0.f, s1 = 0.f;
    for (int n2 = start; n2 < end; n2++) {
      uint u = ((const uint*)(hb + (size_t)n2 * 256))[t];
      s0 += bflo(u);
      s1 += bfhi(u);
    }
    float invc = 1.f / fmaxf((float)(end - start), 1.f);
    sp[2 * t] = s0 * invc;
    sp[2 * t + 1] = s1 * invc;
  }
  __syncthreads();
  if (t < TASKS) {
    float o = bl[t];
    for (int c = 0; c < 256; c++) o += sp[c] * Wl[c * 12 + t];
    out[(size_t)g * 12 + t] = o;
  }
}

// ---------------------------------------------------------------------------
extern "C" void kernel_launch(void* const* d_in, const int* in_sizes, int n_in,
                              void* d_out, int out_size, void* d_ws, size_t ws_size,
                              hipStream_t stream) {
  const float* x = (const float*)d_in[0];
  const int* ei = (const int*)d_in[1];
  const float* ea = (const float*)d_in[2];
  const int* batch = (const int*)d_in[3];
  const float* W1 = (const float*)d_in[4];
  const float* as1 = (const float*)d_in[5];
  const float* ad1 = (const float*)d_in[6];
  const float* We1 = (const float*)d_in[7];
  const float* ae1 = (const float*)d_in[8];
  const float* b1 = (const float*)d_in[9];
  const float* W2 = (const float*)d_in[10];
  const float* as2 = (const float*)d_in[11];
  const float* ad2 = (const float*)d_in[12];
  const float* We2 = (const float*)d_in[13];
  const float* ae2 = (const float*)d_in[14];
  const float* b2 = (const float*)d_in[15];
  const float* Wl = (const float*)d_in[16];
  const float* bl = (const float*)d_in[17];
  float* out = (float*)d_out;

  // workspace carve-up (256B aligned)
  char* ws = (char*)d_ws;
  size_t off = 0;
  auto take = [&](size_t bytes) -> char* {
    char* p = ws + off;
    off = (off + bytes + 255) & ~(size_t)255;
    return p;
  };
  float* msum = (float*)take(8 * 4);
  int* deg = (int*)take((size_t)NN * 4);
  int* cursor = (int*)take((size_t)NN * 4);
  size_t zero_end = off;  // msum+deg+cursor need zeroing
  int* rowptr = (int*)take((size_t)(NN + 1) * 4);
  int* bsums = (int*)take(256 * 4);
  int* csrc = (int*)take((size_t)EE * 4);
  int* eslot = (int*)take((size_t)EE * 4);
  float* exa = (float*)take((size_t)EE * 4 * 4);
  float* p1 = (float*)take(32 * 4);
  float* p2 = (float*)take(32 * 4);
  float* als = (float*)take((size_t)NN * 4 * 4);
  float* ald = (float*)take((size_t)NN * 4 * 4);
  unsigned short* hb = (unsigned short*)take((size_t)NN * 256 * 2);  // GEMM out (bf16)
  unsigned short* ab = (unsigned short*)take((size_t)NN * 256 * 2);  // agg out (bf16)
  unsigned short* xb = (unsigned short*)take((size_t)NN * 32 * 2);
  unsigned short* w1t = (unsigned short*)take((size_t)256 * 32 * 2);
  unsigned short* w2t = (unsigned short*)take((size_t)256 * 256 * 2);
  (void)ws_size;

  hipMemsetAsync(ws, 0, zero_end, stream);

  const int nbN = (NN + 255) / 256;  // 196
  const int nbE = (EE + 255) / 256;  // 1563

  k_pre<<<NBDEG + NBMEAN + NBX + NW1 + NW2, 256, 0, stream>>>(ei + EE, ea, x, W1, W2,
                                                              deg, msum, xb, w1t, w2t);
  k_scan1<<<nbN, 256, 0, stream>>>(deg, rowptr, bsums);
  k_scan23<<<nbN, 256, 0, stream>>>(rowptr, bsums, nbN);
  k_scatparams<<<NBDEG + 2, 256, 0, stream>>>(ei, rowptr, cursor, csrc, eslot,
                                              We1, ae1, We2, ae2, msum, p1, p2);

  const int gb = (NN + 127) / 128;  // 391 GEMM blocks

  // Layer 1
  k_gemm_mfma<<<gb, 256, 0, stream>>>(xb, w1t, as1, ad1, hb, als, ald, NN, 32);
  k_edge<<<nbE, 256, 0, stream>>>(ei, ea, als, ald, eslot, p1, exa);
  k_agg<<<NN / 4, 256, 0, stream>>>(hb, als, ald, rowptr, csrc, exa, p1, b1, ab);

  // Layer 2
  k_gemm_mfma<<<gb, 256, 0, stream>>>(ab, w2t, as2, ad2, hb, als, ald, NN, 256);
  k_edge<<<nbE, 256, 0, stream>>>(ei, ea, als, ald, eslot, p2, exa);
  k_agg<<<NN / 4, 256, 0, stream>>>(hb, als, ald, rowptr, csrc, exa, p2, b2, ab);

  // Pool + readout
  k_pool<<<GG, 256, 0, stream>>>(ab, batch, Wl, bl, out);
}

// Round 9
// 330.301 us; speedup vs baseline: 1.0355x; 1.0355x over previous
//
#include <hip/hip_runtime.h>
#include <math.h>

// Problem constants (fixed by reference)
static constexpr int NN = 50000;   // nodes
static constexpr int EE = 400000;  // edges (without self loops)
static constexpr int GG = 2048;    // graphs
static constexpr int TASKS = 12;

typedef __attribute__((ext_vector_type(8))) short short8;   // 8 bf16 (4 VGPRs)
typedef __attribute__((ext_vector_type(4))) float floatx4;  // MFMA acc

__device__ __forceinline__ unsigned short f2bf(float f) {
  unsigned u = __float_as_uint(f);
  u = u + 0x7fffu + ((u >> 16) & 1u);  // RNE
  return (unsigned short)(u >> 16);
}
__device__ __forceinline__ float bflo(unsigned u) { return __uint_as_float(u << 16); }
__device__ __forceinline__ float bfhi(unsigned u) { return __uint_as_float(u & 0xffff0000u); }

// ---------------------------------------------------------------------------
// Fused independent preamble, grid-partitioned:
//   [0,NBDEG)       in-degree histogram (distributed atomics — safe)
//   [+NBMEAN)       edge_attr mean sums (LDS pre-reduce, 6 atomics/blk — R5 lesson)
//   [+NBX)          x -> bf16 [NN][32] zero-padded (8 outputs/thread)
//   [+NW1)          W1 -> bf16^T [256][32]
//   [+NW2)          W2 -> bf16^T [256][256]
static constexpr int NBDEG = (EE + 255) / 256;     // 1563
static constexpr int NBMEAN = 256;
static constexpr int NBX = (NN * 4 + 255) / 256;   // 782 (thread = 8 bf16 outs)
static constexpr int NW1 = 32;
static constexpr int NW2 = 256;
__global__ void k_pre(const int* __restrict__ dst, const float* __restrict__ ea,
                      const float* __restrict__ x, const float* __restrict__ W1,
                      const float* __restrict__ W2, int* __restrict__ deg,
                      float* __restrict__ msum, unsigned short* __restrict__ xb,
                      unsigned short* __restrict__ w1t, unsigned short* __restrict__ w2t) {
  const int b = blockIdx.x;
  const int t = threadIdx.x;
  if (b < NBDEG) {
    int e = b * 256 + t;
    if (e < EE) atomicAdd(&deg[dst[e]], 1);
  } else if (b < NBDEG + NBMEAN) {
    float s[6] = {0, 0, 0, 0, 0, 0};
    for (int e = (b - NBDEG) * 256 + t; e < EE; e += NBMEAN * 256) {
#pragma unroll
      for (int d = 0; d < 6; d++) s[d] += ea[(size_t)e * 6 + d];
    }
    __shared__ float ls[6];
    if (t < 6) ls[t] = 0.f;
    __syncthreads();
#pragma unroll
    for (int d = 0; d < 6; d++) atomicAdd(&ls[d], s[d]);
    __syncthreads();
    if (t < 6) atomicAdd(&msum[t], ls[t]);
  } else if (b < NBDEG + NBMEAN + NBX) {
    int i = (b - NBDEG - NBMEAN) * 256 + t;  // i indexes 8-element chunks
    if (i < NN * 4) {
      int n = i >> 2, seg = i & 3;
      unsigned short v[8];
#pragma unroll
      for (int j = 0; j < 8; j++) {
        int k = seg * 8 + j;
        v[j] = (k < 29) ? f2bf(x[(size_t)n * 29 + k]) : (unsigned short)0;
      }
      *(short8*)(xb + (size_t)n * 32 + seg * 8) = *(short8*)v;
    }
  } else if (b < NBDEG + NBMEAN + NBX + NW1) {
    int i = (b - NBDEG - NBMEAN - NBX) * 256 + t;
    int n = i >> 5, k = i & 31;
    w1t[i] = (k < 29) ? f2bf(W1[(size_t)k * 256 + n]) : (unsigned short)0;
  } else {
    int i = (b - NBDEG - NBMEAN - NBX - NW1) * 256 + t;
    int n = i >> 8, k = i & 255;
    w2t[i] = f2bf(W2[(size_t)k * 256 + n]);
  }
}

// block-level exclusive scan of deg -> rowptr (partial), block totals -> bsums
__global__ void k_scan1(const int* __restrict__ deg, int* __restrict__ rowptr, int* __restrict__ bsums) {
  __shared__ int sh[256];
  int i = blockIdx.x * 256 + threadIdx.x;
  int v = (i < NN) ? deg[i] : 0;
  sh[threadIdx.x] = v;
  __syncthreads();
  for (int off = 1; off < 256; off <<= 1) {
    int t = (threadIdx.x >= off) ? sh[threadIdx.x - off] : 0;
    __syncthreads();
    sh[threadIdx.x] += t;
    __syncthreads();
  }
  if (i < NN) rowptr[i] = sh[threadIdx.x] - v;  // exclusive within block
  if (threadIdx.x == 255) bsums[blockIdx.x] = sh[255];
}

// fused scan2+scan3: every block redundantly scans the 196 block sums,
// then applies its own block's exclusive prefix to rowptr.
__global__ void k_scan23(int* __restrict__ rowptr, const int* __restrict__ bsums, int nb) {
  __shared__ int sh[256];
  const int t = threadIdx.x;
  sh[t] = (t < nb) ? bsums[t] : 0;
  __syncthreads();
  for (int off = 1; off < 256; off <<= 1) {
    int tv = (t >= off) ? sh[t - off] : 0;
    __syncthreads();
    sh[t] += tv;  // inclusive scan
    __syncthreads();
  }
  const int add = (blockIdx.x == 0) ? 0 : sh[blockIdx.x - 1];
  int i = blockIdx.x * 256 + t;
  if (i < NN) rowptr[i] += add;
  if (i == 0) rowptr[NN] = EE;
}

// scatter edges into CSR-by-dst (+ per-layer params in 2 trailing blocks)
__global__ void k_scatparams(const int* __restrict__ ei, const int* __restrict__ rowptr,
                             int* __restrict__ cursor, int* __restrict__ csrc,
                             int* __restrict__ eslot, const float* __restrict__ We1,
                             const float* __restrict__ ae1, const float* __restrict__ We2,
                             const float* __restrict__ ae2, const float* __restrict__ msum,
                             float* __restrict__ p1, float* __restrict__ p2) {
  const int b = blockIdx.x;
  const int t = threadIdx.x;
  if (b < NBDEG) {
    int e = b * 256 + t;
    if (e >= EE) return;
    int s = ei[e];
    int d = ei[EE + e];
    int p = atomicAdd(&cursor[d], 1);
    int slot = rowptr[d] + p;
    csrc[slot] = s;
    eslot[e] = slot;
  } else {
    const int layer = b - NBDEG;
    const float* We = layer ? We2 : We1;
    const float* ae = layer ? ae2 : ae1;
    float* params = layer ? p2 : p1;
    __shared__ float vsh[24];
    if (t < 24) {
      int d = t >> 2, h = t & 3;
      float s = 0.f;
      for (int c = 0; c < 64; c++) s += We[d * 256 + h * 64 + c] * ae[h * 64 + c];
      vsh[t] = s;
      params[t] = s;
    }
    __syncthreads();
    if (t < 4) {
      float s = 0.f;
      const float invE = 1.0f / (float)EE;
#pragma unroll
      for (int d = 0; d < 6; d++) s += (msum[d] * invE) * vsh[d * 4 + t];
      params[24 + t] = s;
    }
  }
}

// LDS-free bf16 MFMA GEMM: Y[M,256](bf16) = A[M,KP] @ Bt[256,KP] (both bf16, B^T).
// BM=64 (782 blocks = ~3 blocks/CU for occupancy; R8's BM=128/391-block version sat at
// 7% occupancy, latency-bound), BN=256; 4 waves; wave w owns cols [64w,64w+64) = head w.
// Compile-time KP + explicit 2-deep register double-buffer: phase k+1's 8 fragment
// loads issue before phase k's 16 MFMAs, so load latency overlaps compute even at
// low occupancy. No LDS, no __syncthreads. Fused per-head logits als/ald in epilogue.
template <int KP>
__global__ __launch_bounds__(256, 3) void k_gemm_mfma(
    const unsigned short* __restrict__ A, const unsigned short* __restrict__ Bt,
    const float* __restrict__ a_s, const float* __restrict__ a_d,
    unsigned short* __restrict__ Y, float* __restrict__ als, float* __restrict__ ald,
    int M) {
  const int tid = threadIdx.x;
  const int lane = tid & 63;
  const int w = tid >> 6;
  const int l15 = lane & 15;
  const int quad = lane >> 4;
  const int row0 = blockIdx.x * 64;

  floatx4 acc[4][4];
#pragma unroll
  for (int i = 0; i < 4; i++)
#pragma unroll
    for (int j = 0; j < 4; j++) acc[i][j] = {0.f, 0.f, 0.f, 0.f};

  const unsigned short* pa[4];
  const unsigned short* pb[4];
#pragma unroll
  for (int i = 0; i < 4; i++) {
    int r = row0 + i * 16 + l15;
    if (r >= M) r = M - 1;  // clamp: harmless read, stores guarded below
    pa[i] = A + (size_t)r * KP + quad * 8;
  }
#pragma unroll
  for (int j = 0; j < 4; j++) pb[j] = Bt + (size_t)(w * 64 + j * 16 + l15) * KP + quad * 8;

  constexpr int NPH = KP / 32;
  short8 af[2][4], bfr[2][4];
#pragma unroll
  for (int i = 0; i < 4; i++) af[0][i] = *(const short8*)pa[i];
#pragma unroll
  for (int j = 0; j < 4; j++) bfr[0][j] = *(const short8*)pb[j];
#pragma unroll
  for (int ph = 0; ph < NPH; ph++) {
    const int cur = ph & 1, nxt = cur ^ 1;
    if (ph + 1 < NPH) {  // prefetch next phase while this phase's MFMAs run
#pragma unroll
      for (int i = 0; i < 4; i++) {
        pa[i] += 32;
        af[nxt][i] = *(const short8*)pa[i];
      }
#pragma unroll
      for (int j = 0; j < 4; j++) {
        pb[j] += 32;
        bfr[nxt][j] = *(const short8*)pb[j];
      }
    }
#pragma unroll
    for (int i = 0; i < 4; i++)
#pragma unroll
      for (int j = 0; j < 4; j++)
        acc[i][j] = __builtin_amdgcn_mfma_f32_16x16x32_bf16(af[cur][i], bfr[cur][j], acc[i][j], 0, 0, 0);
  }
  // epilogue: C/D layout (m89) col = lane&15, row = (lane>>4)*4 + reg.
  // Wave w's cols w*64+j*16+l15 are exactly head w -> per-head dot reduces in-wave.
  float asc[4], adc[4];
#pragma unroll
  for (int j = 0; j < 4; j++) {
    asc[j] = a_s[w * 64 + j * 16 + l15];
    adc[j] = a_d[w * 64 + j * 16 + l15];
  }
#pragma unroll
  for (int i = 0; i < 4; i++) {
#pragma unroll
    for (int r = 0; r < 4; r++) {
      const int row = row0 + i * 16 + quad * 4 + r;
      unsigned ub[4];
      float hv[4];
#pragma unroll
      for (int j = 0; j < 4; j++) {
        ub[j] = f2bf(acc[i][j][r]);
        hv[j] = __uint_as_float(ub[j] << 16);  // dot uses the rounded value (matches agg reads)
      }
      if (row < M) {
#pragma unroll
        for (int j = 0; j < 4; j++) Y[(size_t)row * 256 + w * 64 + j * 16 + l15] = (unsigned short)ub[j];
      }
      float ps = hv[0] * asc[0] + hv[1] * asc[1] + hv[2] * asc[2] + hv[3] * asc[3];
      float pd = hv[0] * adc[0] + hv[1] * adc[1] + hv[2] * adc[2] + hv[3] * adc[3];
#pragma unroll
      for (int off = 1; off < 16; off <<= 1) {
        ps += __shfl_xor(ps, off, 64);
        pd += __shfl_xor(pd, off, 64);
      }
      if (l15 == 0 && row < M) {
        als[row * 4 + w] = ps;
        ald[row * 4 + w] = pd;
      }
    }
  }
}

__device__ __forceinline__ float leaky02(float x) { return x > 0.f ? x : 0.2f * x; }

// per-edge exp(leaky(logit)) written in CSR slot order.
// Logits are O(1) (0.1-scaled weights) so no max-subtraction needed; exp can't overflow.
__global__ void k_edge(const int* __restrict__ ei, const float* __restrict__ ea,
                       const float* __restrict__ als, const float* __restrict__ ald,
                       const int* __restrict__ eslot, const float* __restrict__ params,
                       float* __restrict__ exa) {
  int e = blockIdx.x * blockDim.x + threadIdx.x;
  if (e >= EE) return;
  int src = ei[e], dst = ei[EE + e];
  float4 s4 = *(const float4*)(als + (size_t)src * 4);
  float4 d4 = *(const float4*)(ald + (size_t)dst * 4);
  float ed[6];
#pragma unroll
  for (int d = 0; d < 6; d++) ed[d] = ea[(size_t)e * 6 + d];
  float sl[4] = {s4.x + d4.x, s4.y + d4.y, s4.z + d4.z, s4.w + d4.w};
  float out[4];
#pragma unroll
  for (int h = 0; h < 4; h++) {
    float x = sl[h];
#pragma unroll
    for (int d = 0; d < 6; d++) x += ed[d] * params[d * 4 + h];
    out[h] = __expf(leaky02(x));
  }
  *(float4*)(exa + (size_t)eslot[e] * 4) = make_float4(out[0], out[1], out[2], out[3]);
}

// GAT aggregation on bf16 h, one wave per node, TWO edges in flight per iteration:
// lanes 0-31 process even CSR slots, 32-63 odd. Lane covers 8 channels (16B load),
// head = sl>>3 so each lane needs exactly one softmax weight per edge.
// out = (Σ ex·h[src] + ex_self·h[n]) / Σ ex, +b, relu -> bf16.
__global__ __launch_bounds__(256) void k_agg(
    const unsigned short* __restrict__ hinb, const float* __restrict__ als,
    const float* __restrict__ ald, const int* __restrict__ rowptr, const int* __restrict__ csrc,
    const float* __restrict__ exa, const float* __restrict__ params, const float* __restrict__ bias,
    unsigned short* __restrict__ houtb) {
  const int lane = threadIdx.x & 63;
  const int n = blockIdx.x * 4 + (threadIdx.x >> 6);
  if (n >= NN) return;
  const int half = lane >> 5;  // 0: even slots, 1: odd slots
  const int sl = lane & 31;    // 16B chunk (8 channels) within row
  const int head = sl >> 3;

  float acc[8];
  float ssum;
  {
    float slg = leaky02(als[n * 4 + head] + ald[n * 4 + head] + params[24 + head]);
    float exs = __expf(slg);
    float wgt = (half == 0) ? exs : 0.f;  // self term counted once (cross-half merge later)
    ssum = wgt;
    uint4 uv = *(const uint4*)(hinb + (size_t)n * 256 + sl * 8);
    acc[0] = bflo(uv.x) * wgt;
    acc[1] = bfhi(uv.x) * wgt;
    acc[2] = bflo(uv.y) * wgt;
    acc[3] = bfhi(uv.y) * wgt;
    acc[4] = bflo(uv.z) * wgt;
    acc[5] = bfhi(uv.z) * wgt;
    acc[6] = bflo(uv.w) * wgt;
    acc[7] = bfhi(uv.w) * wgt;
  }
  const int end = rowptr[n + 1];
  int s = rowptr[n] + half;
  int sn = 0;
  float ex = 0.f;
  if (s < end) {
    sn = csrc[s];
    ex = exa[(size_t)s * 4 + head];
  }
  while (s < end) {
    const int sc = sn;
    const float exc = ex;
    const int s2 = s + 2;
    if (s2 < end) {  // prefetch next slot's metadata
      sn = csrc[s2];
      ex = exa[(size_t)s2 * 4 + head];
    }
    uint4 uv = *(const uint4*)(hinb + (size_t)sc * 256 + sl * 8);
    acc[0] += bflo(uv.x) * exc;
    acc[1] += bfhi(uv.x) * exc;
    acc[2] += bflo(uv.y) * exc;
    acc[3] += bfhi(uv.y) * exc;
    acc[4] += bflo(uv.z) * exc;
    acc[5] += bfhi(uv.z) * exc;
    acc[6] += bflo(uv.w) * exc;
    acc[7] += bfhi(uv.w) * exc;
    ssum += exc;
    s = s2;
  }
  // merge even/odd halves (same channel set lives at lane and lane^32)
#pragma unroll
  for (int j = 0; j < 8; j++) acc[j] += __shfl_xor(acc[j], 32, 64);
  ssum += __shfl_xor(ssum, 32, 64);
  if (half == 0) {
    const float inv = 1.f / (ssum + 1e-16f);
    float4 b0 = *(const float4*)(bias + sl * 8);
    float4 b1 = *(const float4*)(bias + sl * 8 + 4);
    const float bb[8] = {b0.x, b0.y, b0.z, b0.w, b1.x, b1.y, b1.z, b1.w};
    uint p[4];
#pragma unroll
    for (int j = 0; j < 4; j++) {
      float e0 = fmaxf(acc[2 * j] * inv + bb[2 * j], 0.f);
      float e1 = fmaxf(acc[2 * j + 1] * inv + bb[2 * j + 1], 0.f);
      p[j] = (uint)f2bf(e0) | ((uint)f2bf(e1) << 16);
    }
    *(uint4*)(houtb + (size_t)n * 256 + sl * 8) = make_uint4(p[0], p[1], p[2], p[3]);
  }
}

// per-graph mean pool (bf16 in) + readout linear (256->12)
__global__ __launch_bounds__(256) void k_pool(const unsigned short* __restrict__ hb,
                                              const int* __restrict__ batch,
                                              const float* __restrict__ Wl,
                                              const float* __restrict__ bl,
                                              float* __restrict__ out) {
  int g = blockIdx.x;
  int t = threadIdx.x;
  int lo = 0, hi = NN;
  while (lo < hi) {
    int mid = (lo + hi) >> 1;
    if (batch[mid] < g) lo = mid + 1; else hi = mid;
  }
  int start = lo;
  hi = NN;
  while (lo < hi) {
    int mid = (lo + hi) >> 1;
    if (batch[mid] < g + 1) lo = mid + 1; else hi = mid;
  }
  int end = lo;
  __shared__ float sp[256];
  if (t < 128) {
    float s0 = 0.f, s1 = 0.f;
    for (int n2 = start; n2 < end; n2++) {
      uint u = ((const uint*)(hb + (size_t)n2 * 256))[t];
      s0 += bflo(u);
      s1 += bfhi(u);
    }
    float invc = 1.f / fmaxf((float)(end - start), 1.f);
    sp[2 * t] = s0 * invc;
    sp[2 * t + 1] = s1 * invc;
  }
  __syncthreads();
  if (t < TASKS) {
    float o = bl[t];
    for (int c = 0; c < 256; c++) o += sp[c] * Wl[c * 12 + t];
    out[(size_t)g * 12 + t] = o;
  }
}

// ---------------------------------------------------------------------------
extern "C" void kernel_launch(void* const* d_in, const int* in_sizes, int n_in,
                              void* d_out, int out_size, void* d_ws, size_t ws_size,
                              hipStream_t stream) {
  const float* x = (const float*)d_in[0];
  const int* ei = (const int*)d_in[1];
  const float* ea = (const float*)d_in[2];
  const int* batch = (const int*)d_in[3];
  const float* W1 = (const float*)d_in[4];
  const float* as1 = (const float*)d_in[5];
  const float* ad1 = (const float*)d_in[6];
  const float* We1 = (const float*)d_in[7];
  const float* ae1 = (const float*)d_in[8];
  const float* b1 = (const float*)d_in[9];
  const float* W2 = (const float*)d_in[10];
  const float* as2 = (const float*)d_in[11];
  const float* ad2 = (const float*)d_in[12];
  const float* We2 = (const float*)d_in[13];
  const float* ae2 = (const float*)d_in[14];
  const float* b2 = (const float*)d_in[15];
  const float* Wl = (const float*)d_in[16];
  const float* bl = (const float*)d_in[17];
  float* out = (float*)d_out;

  // workspace carve-up (256B aligned)
  char* ws = (char*)d_ws;
  size_t off = 0;
  auto take = [&](size_t bytes) -> char* {
    char* p = ws + off;
    off = (off + bytes + 255) & ~(size_t)255;
    return p;
  };
  float* msum = (float*)take(8 * 4);
  int* deg = (int*)take((size_t)NN * 4);
  int* cursor = (int*)take((size_t)NN * 4);
  size_t zero_end = off;  // msum+deg+cursor need zeroing
  int* rowptr = (int*)take((size_t)(NN + 1) * 4);
  int* bsums = (int*)take(256 * 4);
  int* csrc = (int*)take((size_t)EE * 4);
  int* eslot = (int*)take((size_t)EE * 4);
  float* exa = (float*)take((size_t)EE * 4 * 4);
  float* p1 = (float*)take(32 * 4);
  float* p2 = (float*)take(32 * 4);
  float* als = (float*)take((size_t)NN * 4 * 4);
  float* ald = (float*)take((size_t)NN * 4 * 4);
  unsigned short* hb = (unsigned short*)take((size_t)NN * 256 * 2);  // GEMM out (bf16)
  unsigned short* ab = (unsigned short*)take((size_t)NN * 256 * 2);  // agg out (bf16)
  unsigned short* xb = (unsigned short*)take((size_t)NN * 32 * 2);
  unsigned short* w1t = (unsigned short*)take((size_t)256 * 32 * 2);
  unsigned short* w2t = (unsigned short*)take((size_t)256 * 256 * 2);
  (void)ws_size;

  hipMemsetAsync(ws, 0, zero_end, stream);

  const int nbN = (NN + 255) / 256;  // 196
  const int nbE = (EE + 255) / 256;  // 1563

  k_pre<<<NBDEG + NBMEAN + NBX + NW1 + NW2, 256, 0, stream>>>(ei + EE, ea, x, W1, W2,
                                                              deg, msum, xb, w1t, w2t);
  k_scan1<<<nbN, 256, 0, stream>>>(deg, rowptr, bsums);
  k_scan23<<<nbN, 256, 0, stream>>>(rowptr, bsums, nbN);
  k_scatparams<<<NBDEG + 2, 256, 0, stream>>>(ei, rowptr, cursor, csrc, eslot,
                                              We1, ae1, We2, ae2, msum, p1, p2);

  const int gb = (NN + 63) / 64;  // 782 GEMM blocks (~3 blocks/CU)

  // Layer 1
  k_gemm_mfma<32><<<gb, 256, 0, stream>>>(xb, w1t, as1, ad1, hb, als, ald, NN);
  k_edge<<<nbE, 256, 0, stream>>>(ei, ea, als, ald, eslot, p1, exa);
  k_agg<<<NN / 4, 256, 0, stream>>>(hb, als, ald, rowptr, csrc, exa, p1, b1, ab);

  // Layer 2
  k_gemm_mfma<256><<<gb, 256, 0, stream>>>(ab, w2t, as2, ad2, hb, als, ald, NN);
  k_edge<<<nbE, 256, 0, stream>>>(ei, ea, als, ald, eslot, p2, exa);
  k_agg<<<NN / 4, 256, 0, stream>>>(hb, als, ald, rowptr, csrc, exa, p2, b2, ab);

  // Pool + readout
  k_pool<<<GG, 256, 0, stream>>>(ab, batch, Wl, bl, out);
}

// Round 10
// 315.233 us; speedup vs baseline: 1.0849x; 1.0478x over previous
//
#include <hip/hip_runtime.h>
#include <math.h>

// Problem constants (fixed by reference)
static constexpr int NN = 50000;   // nodes
static constexpr int EE = 400000;  // edges (without self loops)
static constexpr int GG = 2048;    // graphs
static constexpr int TASKS = 12;

typedef __attribute__((ext_vector_type(8))) short short8;   // 8 bf16 (4 VGPRs)
typedef __attribute__((ext_vector_type(4))) float floatx4;  // MFMA acc

__device__ __forceinline__ unsigned short f2bf(float f) {
  unsigned u = __float_as_uint(f);
  u = u + 0x7fffu + ((u >> 16) & 1u);  // RNE
  return (unsigned short)(u >> 16);
}
__device__ __forceinline__ float bflo(unsigned u) { return __uint_as_float(u << 16); }
__device__ __forceinline__ float bfhi(unsigned u) { return __uint_as_float(u & 0xffff0000u); }

// ---------------------------------------------------------------------------
// Fused independent preamble, grid-partitioned:
//   [0,NBDEG)       in-degree histogram (distributed atomics — safe)
//   [+NBMEAN)       edge_attr mean sums (LDS pre-reduce, 6 atomics/blk — R5 lesson)
//   [+NBX)          x -> bf16 [NN][32] zero-padded (8 outputs/thread)
//   [+NW1)          W1 -> bf16 fragment-tiled [row>>4][kc][row&15][8], K=32
//   [+NW2)          W2 -> bf16 fragment-tiled [row>>4][kc][row&15][8], K=256
// Tiled layout makes each GEMM B-fragment load a contiguous 1KB wave burst
// (R9's B^T row-major gave 16 scattered 64B requests per load instr).
static constexpr int NBDEG = (EE + 255) / 256;     // 1563
static constexpr int NBMEAN = 256;
static constexpr int NBX = (NN * 4 + 255) / 256;   // 782 (thread = 8 bf16 outs)
static constexpr int NW1 = 32;
static constexpr int NW2 = 256;
__global__ void k_pre(const int* __restrict__ dst, const float* __restrict__ ea,
                      const float* __restrict__ x, const float* __restrict__ W1,
                      const float* __restrict__ W2, int* __restrict__ deg,
                      float* __restrict__ msum, unsigned short* __restrict__ xb,
                      unsigned short* __restrict__ w1t, unsigned short* __restrict__ w2t) {
  const int b = blockIdx.x;
  const int t = threadIdx.x;
  if (b < NBDEG) {
    int e = b * 256 + t;
    if (e < EE) atomicAdd(&deg[dst[e]], 1);
  } else if (b < NBDEG + NBMEAN) {
    float s[6] = {0, 0, 0, 0, 0, 0};
    for (int e = (b - NBDEG) * 256 + t; e < EE; e += NBMEAN * 256) {
#pragma unroll
      for (int d = 0; d < 6; d++) s[d] += ea[(size_t)e * 6 + d];
    }
    __shared__ float ls[6];
    if (t < 6) ls[t] = 0.f;
    __syncthreads();
#pragma unroll
    for (int d = 0; d < 6; d++) atomicAdd(&ls[d], s[d]);
    __syncthreads();
    if (t < 6) atomicAdd(&msum[t], ls[t]);
  } else if (b < NBDEG + NBMEAN + NBX) {
    int i = (b - NBDEG - NBMEAN) * 256 + t;  // i indexes 8-element chunks
    if (i < NN * 4) {
      int n = i >> 2, seg = i & 3;
      unsigned short v[8];
#pragma unroll
      for (int j = 0; j < 8; j++) {
        int k = seg * 8 + j;
        v[j] = (k < 29) ? f2bf(x[(size_t)n * 29 + k]) : (unsigned short)0;
      }
      *(short8*)(xb + (size_t)n * 32 + seg * 8) = *(short8*)v;
    }
  } else if (b < NBDEG + NBMEAN + NBX + NW1) {
    int i = (b - NBDEG - NBMEAN - NBX) * 256 + t;  // 8192 elems
    int row = i >> 5, k = i & 31;
    unsigned short v = (k < 29) ? f2bf(W1[(size_t)k * 256 + row]) : (unsigned short)0;
    w1t[((row >> 4) * 4 + (k >> 3)) * 128 + (row & 15) * 8 + (k & 7)] = v;
  } else {
    int i = (b - NBDEG - NBMEAN - NBX - NW1) * 256 + t;  // 65536 elems
    int row = i >> 8, k = i & 255;
    w2t[((row >> 4) * 32 + (k >> 3)) * 128 + (row & 15) * 8 + (k & 7)] = f2bf(W2[(size_t)k * 256 + row]);
  }
}

// block-level exclusive scan of deg -> rowptr (partial), block totals -> bsums
__global__ void k_scan1(const int* __restrict__ deg, int* __restrict__ rowptr, int* __restrict__ bsums) {
  __shared__ int sh[256];
  int i = blockIdx.x * 256 + threadIdx.x;
  int v = (i < NN) ? deg[i] : 0;
  sh[threadIdx.x] = v;
  __syncthreads();
  for (int off = 1; off < 256; off <<= 1) {
    int t = (threadIdx.x >= off) ? sh[threadIdx.x - off] : 0;
    __syncthreads();
    sh[threadIdx.x] += t;
    __syncthreads();
  }
  if (i < NN) rowptr[i] = sh[threadIdx.x] - v;  // exclusive within block
  if (threadIdx.x == 255) bsums[blockIdx.x] = sh[255];
}

// fused scan2+scan3: every block redundantly scans the 196 block sums,
// then applies its own block's exclusive prefix to rowptr.
__global__ void k_scan23(int* __restrict__ rowptr, const int* __restrict__ bsums, int nb) {
  __shared__ int sh[256];
  const int t = threadIdx.x;
  sh[t] = (t < nb) ? bsums[t] : 0;
  __syncthreads();
  for (int off = 1; off < 256; off <<= 1) {
    int tv = (t >= off) ? sh[t - off] : 0;
    __syncthreads();
    sh[t] += tv;  // inclusive scan
    __syncthreads();
  }
  const int add = (blockIdx.x == 0) ? 0 : sh[blockIdx.x - 1];
  int i = blockIdx.x * 256 + t;
  if (i < NN) rowptr[i] += add;
  if (i == 0) rowptr[NN] = EE;
}

// ---------------------------------------------------------------------------
// GEMM body (device fn): Y[M,256](bf16) = A[M,KP](bf16 row-major) @ B(tiled)
// + fused per-head logits. BM=64; 4 waves; wave w owns cols [64w,64w+64) = head w.
// B frags: contiguous 1KB wave bursts from the tiled layout. A frags: direct
// global (scattered but only 25MB total). 2-deep register double-buffer;
// requires >=160 VGPRs — callers use __launch_bounds__(256,2) (R9's (256,3)
// capped VGPR at 72 and the compiler deleted the pipeline).
template <int KP>
__device__ __forceinline__ void gemm_body(
    int bx, const unsigned short* __restrict__ A, const unsigned short* __restrict__ Bt,
    const float* __restrict__ a_s, const float* __restrict__ a_d,
    unsigned short* __restrict__ Y, float* __restrict__ als, float* __restrict__ ald, int M) {
  const int tid = threadIdx.x;
  const int lane = tid & 63;
  const int w = tid >> 6;
  const int l15 = lane & 15;
  const int quad = lane >> 4;
  const int row0 = bx * 64;

  floatx4 acc[4][4];
#pragma unroll
  for (int i = 0; i < 4; i++)
#pragma unroll
    for (int j = 0; j < 4; j++) acc[i][j] = {0.f, 0.f, 0.f, 0.f};

  const unsigned short* pa[4];
  const unsigned short* pb[4];
#pragma unroll
  for (int i = 0; i < 4; i++) {
    int r = row0 + i * 16 + l15;
    if (r >= M) r = M - 1;  // clamp: harmless read, stores guarded below
    pa[i] = A + (size_t)r * KP + quad * 8;
  }
#pragma unroll
  for (int j = 0; j < 4; j++)
    pb[j] = Bt + (size_t)((w * 4 + j) * (KP / 8) + quad) * 128 + l15 * 8;

  constexpr int NPH = KP / 32;
  short8 af[2][4], bfr[2][4];
#pragma unroll
  for (int i = 0; i < 4; i++) af[0][i] = *(const short8*)pa[i];
#pragma unroll
  for (int j = 0; j < 4; j++) bfr[0][j] = *(const short8*)pb[j];
#pragma unroll
  for (int ph = 0; ph < NPH; ph++) {
    const int cur = ph & 1, nxt = cur ^ 1;
    if (ph + 1 < NPH) {  // prefetch next phase while this phase's MFMAs run
#pragma unroll
      for (int i = 0; i < 4; i++) {
        pa[i] += 32;
        af[nxt][i] = *(const short8*)pa[i];
      }
#pragma unroll
      for (int j = 0; j < 4; j++) {
        pb[j] += 512;  // 4 kc * 128
        bfr[nxt][j] = *(const short8*)pb[j];
      }
    }
#pragma unroll
    for (int i = 0; i < 4; i++)
#pragma unroll
      for (int j = 0; j < 4; j++)
        acc[i][j] = __builtin_amdgcn_mfma_f32_16x16x32_bf16(af[cur][i], bfr[cur][j], acc[i][j], 0, 0, 0);
  }
  // epilogue: C/D layout (m89) col = lane&15, row = (lane>>4)*4 + reg.
  float asc[4], adc[4];
#pragma unroll
  for (int j = 0; j < 4; j++) {
    asc[j] = a_s[w * 64 + j * 16 + l15];
    adc[j] = a_d[w * 64 + j * 16 + l15];
  }
#pragma unroll
  for (int i = 0; i < 4; i++) {
#pragma unroll
    for (int r = 0; r < 4; r++) {
      const int row = row0 + i * 16 + quad * 4 + r;
      unsigned ub[4];
      float hv[4];
#pragma unroll
      for (int j = 0; j < 4; j++) {
        ub[j] = f2bf(acc[i][j][r]);
        hv[j] = __uint_as_float(ub[j] << 16);  // dot uses rounded value (matches agg reads)
      }
      if (row < M) {
#pragma unroll
        for (int j = 0; j < 4; j++) Y[(size_t)row * 256 + w * 64 + j * 16 + l15] = (unsigned short)ub[j];
      }
      float ps = hv[0] * asc[0] + hv[1] * asc[1] + hv[2] * asc[2] + hv[3] * asc[3];
      float pd = hv[0] * adc[0] + hv[1] * adc[1] + hv[2] * adc[2] + hv[3] * adc[3];
#pragma unroll
      for (int off = 1; off < 16; off <<= 1) {
        ps += __shfl_xor(ps, off, 64);
        pd += __shfl_xor(pd, off, 64);
      }
      if (l15 == 0 && row < M) {
        als[row * 4 + w] = ps;
        ald[row * 4 + w] = pd;
      }
    }
  }
}

static constexpr int GB = (NN + 63) / 64;  // 782 GEMM blocks

// Fused: CSR scatter (1563 blks) ∥ per-layer params (2 blks) ∥ layer-1 GEMM (782 blks).
// All three partitions are mutually independent; scatter is atomic/memory-bound,
// GEMM is MFMA-bound — good co-residency.
__global__ __launch_bounds__(256, 2) void k_scatgemm1(
    const int* __restrict__ ei, const int* __restrict__ rowptr, int* __restrict__ cursor,
    int* __restrict__ csrc, int* __restrict__ eslot, const float* __restrict__ We1,
    const float* __restrict__ ae1, const float* __restrict__ We2, const float* __restrict__ ae2,
    const float* __restrict__ msum, float* __restrict__ p1, float* __restrict__ p2,
    const unsigned short* __restrict__ xb, const unsigned short* __restrict__ w1t,
    const float* __restrict__ as1, const float* __restrict__ ad1,
    unsigned short* __restrict__ hb, float* __restrict__ als, float* __restrict__ ald) {
  const int b = blockIdx.x;
  const int t = threadIdx.x;
  if (b < NBDEG) {
    int e = b * 256 + t;
    if (e >= EE) return;
    int s = ei[e];
    int d = ei[EE + e];
    int p = atomicAdd(&cursor[d], 1);
    int slot = rowptr[d] + p;
    csrc[slot] = s;
    eslot[e] = slot;
  } else if (b < NBDEG + 2) {
    const int layer = b - NBDEG;
    const float* We = layer ? We2 : We1;
    const float* ae = layer ? ae2 : ae1;
    float* params = layer ? p2 : p1;
    __shared__ float vsh[24];
    if (t < 24) {
      int d = t >> 2, h = t & 3;
      float s = 0.f;
      for (int c = 0; c < 64; c++) s += We[d * 256 + h * 64 + c] * ae[h * 64 + c];
      vsh[t] = s;
      params[t] = s;
    }
    __syncthreads();
    if (t < 4) {
      float s = 0.f;
      const float invE = 1.0f / (float)EE;
#pragma unroll
      for (int d = 0; d < 6; d++) s += (msum[d] * invE) * vsh[d * 4 + t];
      params[24 + t] = s;
    }
  } else {
    gemm_body<32>(b - NBDEG - 2, xb, w1t, as1, ad1, hb, als, ald, NN);
  }
}

// layer-2 GEMM standalone
__global__ __launch_bounds__(256, 2) void k_gemm2(
    const unsigned short* __restrict__ A, const unsigned short* __restrict__ Bt,
    const float* __restrict__ a_s, const float* __restrict__ a_d,
    unsigned short* __restrict__ Y, float* __restrict__ als, float* __restrict__ ald) {
  gemm_body<256>(blockIdx.x, A, Bt, a_s, a_d, Y, als, ald, NN);
}

__device__ __forceinline__ float leaky02(float x) { return x > 0.f ? x : 0.2f * x; }

// per-edge exp(leaky(logit)) written in CSR slot order.
// Logits are O(1) (0.1-scaled weights) so no max-subtraction needed; exp can't overflow.
__global__ void k_edge(const int* __restrict__ ei, const float* __restrict__ ea,
                       const float* __restrict__ als, const float* __restrict__ ald,
                       const int* __restrict__ eslot, const float* __restrict__ params,
                       float* __restrict__ exa) {
  int e = blockIdx.x * blockDim.x + threadIdx.x;
  if (e >= EE) return;
  int src = ei[e], dst = ei[EE + e];
  float4 s4 = *(const float4*)(als + (size_t)src * 4);
  float4 d4 = *(const float4*)(ald + (size_t)dst * 4);
  float ed[6];
#pragma unroll
  for (int d = 0; d < 6; d++) ed[d] = ea[(size_t)e * 6 + d];
  float sl[4] = {s4.x + d4.x, s4.y + d4.y, s4.z + d4.z, s4.w + d4.w};
  float out[4];
#pragma unroll
  for (int h = 0; h < 4; h++) {
    float x = sl[h];
#pragma unroll
    for (int d = 0; d < 6; d++) x += ed[d] * params[d * 4 + h];
    out[h] = __expf(leaky02(x));
  }
  *(float4*)(exa + (size_t)eslot[e] * 4) = make_float4(out[0], out[1], out[2], out[3]);
}

// GAT aggregation on bf16 h, one wave per node, TWO edges in flight per iteration:
// lanes 0-31 process even CSR slots, 32-63 odd. Lane covers 8 channels (16B load),
// head = sl>>3 so each lane needs exactly one softmax weight per edge.
// out = (Σ ex·h[src] + ex_self·h[n]) / Σ ex, +b, relu -> bf16.
__global__ __launch_bounds__(256) void k_agg(
    const unsigned short* __restrict__ hinb, const float* __restrict__ als,
    const float* __restrict__ ald, const int* __restrict__ rowptr, const int* __restrict__ csrc,
    const float* __restrict__ exa, const float* __restrict__ params, const float* __restrict__ bias,
    unsigned short* __restrict__ houtb) {
  const int lane = threadIdx.x & 63;
  const int n = blockIdx.x * 4 + (threadIdx.x >> 6);
  if (n >= NN) return;
  const int half = lane >> 5;  // 0: even slots, 1: odd slots
  const int sl = lane & 31;    // 16B chunk (8 channels) within row
  const int head = sl >> 3;

  float acc[8];
  float ssum;
  {
    float slg = leaky02(als[n * 4 + head] + ald[n * 4 + head] + params[24 + head]);
    float exs = __expf(slg);
    float wgt = (half == 0) ? exs : 0.f;  // self term counted once (cross-half merge later)
    ssum = wgt;
    uint4 uv = *(const uint4*)(hinb + (size_t)n * 256 + sl * 8);
    acc[0] = bflo(uv.x) * wgt;
    acc[1] = bfhi(uv.x) * wgt;
    acc[2] = bflo(uv.y) * wgt;
    acc[3] = bfhi(uv.y) * wgt;
    acc[4] = bflo(uv.z) * wgt;
    acc[5] = bfhi(uv.z) * wgt;
    acc[6] = bflo(uv.w) * wgt;
    acc[7] = bfhi(uv.w) * wgt;
  }
  const int end = rowptr[n + 1];
  int s = rowptr[n] + half;
  int sn = 0;
  float ex = 0.f;
  if (s < end) {
    sn = csrc[s];
    ex = exa[(size_t)s * 4 + head];
  }
  while (s < end) {
    const int sc = sn;
    const float exc = ex;
    const int s2 = s + 2;
    if (s2 < end) {  // prefetch next slot's metadata
      sn = csrc[s2];
      ex = exa[(size_t)s2 * 4 + head];
    }
    uint4 uv = *(const uint4*)(hinb + (size_t)sc * 256 + sl * 8);
    acc[0] += bflo(uv.x) * exc;
    acc[1] += bfhi(uv.x) * exc;
    acc[2] += bflo(uv.y) * exc;
    acc[3] += bfhi(uv.y) * exc;
    acc[4] += bflo(uv.z) * exc;
    acc[5] += bfhi(uv.z) * exc;
    acc[6] += bflo(uv.w) * exc;
    acc[7] += bfhi(uv.w) * exc;
    ssum += exc;
    s = s2;
  }
  // merge even/odd halves (same channel set lives at lane and lane^32)
#pragma unroll
  for (int j = 0; j < 8; j++) acc[j] += __shfl_xor(acc[j], 32, 64);
  ssum += __shfl_xor(ssum, 32, 64);
  if (half == 0) {
    const float inv = 1.f / (ssum + 1e-16f);
    float4 b0 = *(const float4*)(bias + sl * 8);
    float4 b1 = *(const float4*)(bias + sl * 8 + 4);
    const float bb[8] = {b0.x, b0.y, b0.z, b0.w, b1.x, b1.y, b1.z, b1.w};
    uint p[4];
#pragma unroll
    for (int j = 0; j < 4; j++) {
      float e0 = fmaxf(acc[2 * j] * inv + bb[2 * j], 0.f);
      float e1 = fmaxf(acc[2 * j + 1] * inv + bb[2 * j + 1], 0.f);
      p[j] = (uint)f2bf(e0) | ((uint)f2bf(e1) << 16);
    }
    *(uint4*)(houtb + (size_t)n * 256 + sl * 8) = make_uint4(p[0], p[1], p[2], p[3]);
  }
}

// per-graph mean pool (bf16 in) + readout linear (256->12)
__global__ __launch_bounds__(256) void k_pool(const unsigned short* __restrict__ hb,
                                              const int* __restrict__ batch,
                                              const float* __restrict__ Wl,
                                              const float* __restrict__ bl,
                                              float* __restrict__ out) {
  int g = blockIdx.x;
  int t = threadIdx.x;
  int lo = 0, hi = NN;
  while (lo < hi) {
    int mid = (lo + hi) >> 1;
    if (batch[mid] < g) lo = mid + 1; else hi = mid;
  }
  int start = lo;
  hi = NN;
  while (lo < hi) {
    int mid = (lo + hi) >> 1;
    if (batch[mid] < g + 1) lo = mid + 1; else hi = mid;
  }
  int end = lo;
  __shared__ float sp[256];
  if (t < 128) {
    float s0 = 0.f, s1 = 0.f;
    for (int n2 = start; n2 < end; n2++) {
      uint u = ((const uint*)(hb + (size_t)n2 * 256))[t];
      s0 += bflo(u);
      s1 += bfhi(u);
    }
    float invc = 1.f / fmaxf((float)(end - start), 1.f);
    sp[2 * t] = s0 * invc;
    sp[2 * t + 1] = s1 * invc;
  }
  __syncthreads();
  if (t < TASKS) {
    float o = bl[t];
    for (int c = 0; c < 256; c++) o += sp[c] * Wl[c * 12 + t];
    out[(size_t)g * 12 + t] = o;
  }
}

// ---------------------------------------------------------------------------
extern "C" void kernel_launch(void* const* d_in, const int* in_sizes, int n_in,
                              void* d_out, int out_size, void* d_ws, size_t ws_size,
                              hipStream_t stream) {
  const float* x = (const float*)d_in[0];
  const int* ei = (const int*)d_in[1];
  const float* ea = (const float*)d_in[2];
  const int* batch = (const int*)d_in[3];
  const float* W1 = (const float*)d_in[4];
  const float* as1 = (const float*)d_in[5];
  const float* ad1 = (const float*)d_in[6];
  const float* We1 = (const float*)d_in[7];
  const float* ae1 = (const float*)d_in[8];
  const float* b1 = (const float*)d_in[9];
  const float* W2 = (const float*)d_in[10];
  const float* as2 = (const float*)d_in[11];
  const float* ad2 = (const float*)d_in[12];
  const float* We2 = (const float*)d_in[13];
  const float* ae2 = (const float*)d_in[14];
  const float* b2 = (const float*)d_in[15];
  const float* Wl = (const float*)d_in[16];
  const float* bl = (const float*)d_in[17];
  float* out = (float*)d_out;

  // workspace carve-up (256B aligned)
  char* ws = (char*)d_ws;
  size_t off = 0;
  auto take = [&](size_t bytes) -> char* {
    char* p = ws + off;
    off = (off + bytes + 255) & ~(size_t)255;
    return p;
  };
  float* msum = (float*)take(8 * 4);
  int* deg = (int*)take((size_t)NN * 4);
  int* cursor = (int*)take((size_t)NN * 4);
  size_t zero_end = off;  // msum+deg+cursor need zeroing
  int* rowptr = (int*)take((size_t)(NN + 1) * 4);
  int* bsums = (int*)take(256 * 4);
  int* csrc = (int*)take((size_t)EE * 4);
  int* eslot = (int*)take((size_t)EE * 4);
  float* exa = (float*)take((size_t)EE * 4 * 4);
  float* p1 = (float*)take(32 * 4);
  float* p2 = (float*)take(32 * 4);
  float* als = (float*)take((size_t)NN * 4 * 4);
  float* ald = (float*)take((size_t)NN * 4 * 4);
  unsigned short* hb = (unsigned short*)take((size_t)NN * 256 * 2);  // GEMM out (bf16)
  unsigned short* ab = (unsigned short*)take((size_t)NN * 256 * 2);  // agg out (bf16)
  unsigned short* xb = (unsigned short*)take((size_t)NN * 32 * 2);
  unsigned short* w1t = (unsigned short*)take((size_t)256 * 32 * 2);
  unsigned short* w2t = (unsigned short*)take((size_t)256 * 256 * 2);
  (void)ws_size;

  hipMemsetAsync(ws, 0, zero_end, stream);

  const int nbN = (NN + 255) / 256;  // 196
  const int nbE = (EE + 255) / 256;  // 1563

  k_pre<<<NBDEG + NBMEAN + NBX + NW1 + NW2, 256, 0, stream>>>(ei + EE, ea, x, W1, W2,
                                                              deg, msum, xb, w1t, w2t);
  k_scan1<<<nbN, 256, 0, stream>>>(deg, rowptr, bsums);
  k_scan23<<<nbN, 256, 0, stream>>>(rowptr, bsums, nbN);

  // scatter ∥ params ∥ layer-1 GEMM (independent partitions)
  k_scatgemm1<<<NBDEG + 2 + GB, 256, 0, stream>>>(ei, rowptr, cursor, csrc, eslot,
                                                  We1, ae1, We2, ae2, msum, p1, p2,
                                                  xb, w1t, as1, ad1, hb, als, ald);

  // Layer 1 (cont.)
  k_edge<<<nbE, 256, 0, stream>>>(ei, ea, als, ald, eslot, p1, exa);
  k_agg<<<NN / 4, 256, 0, stream>>>(hb, als, ald, rowptr, csrc, exa, p1, b1, ab);

  // Layer 2
  k_gemm2<<<GB, 256, 0, stream>>>(ab, w2t, as2, ad2, hb, als, ald);
  k_edge<<<nbE, 256, 0, stream>>>(ei, ea, als, ald, eslot, p2, exa);
  k_agg<<<NN / 4, 256, 0, stream>>>(hb, als, ald, rowptr, csrc, exa, p2, b2, ab);

  // Pool + readout
  k_pool<<<GG, 256, 0, stream>>>(ab, batch, Wl, bl, out);
}

// Round 11
// 312.538 us; speedup vs baseline: 1.0943x; 1.0086x over previous
//
#include <hip/hip_runtime.h>
#include <math.h>

// Problem constants (fixed by reference)
static constexpr int NN = 50000;   // nodes
static constexpr int EE = 400000;  // edges (without self loops)
static constexpr int GG = 2048;    // graphs
static constexpr int TASKS = 12;

typedef __attribute__((ext_vector_type(8))) short short8;   // 8 bf16 (4 VGPRs)
typedef __attribute__((ext_vector_type(4))) float floatx4;  // MFMA acc

__device__ __forceinline__ unsigned short f2bf(float f) {
  unsigned u = __float_as_uint(f);
  u = u + 0x7fffu + ((u >> 16) & 1u);  // RNE
  return (unsigned short)(u >> 16);
}
__device__ __forceinline__ float bflo(unsigned u) { return __uint_as_float(u << 16); }
__device__ __forceinline__ float bfhi(unsigned u) { return __uint_as_float(u & 0xffff0000u); }

// ---------------------------------------------------------------------------
// Fused independent preamble, grid-partitioned:
//   [0,NBDEG)       in-degree histogram (distributed atomics — safe)
//   [+NBMEAN)       edge_attr mean sums (LDS pre-reduce, 6 atomics/blk — R5 lesson)
//   [+NBX)          x -> bf16 [NN][32] zero-padded (8 outputs/thread)
//   [+NW1)          W1 -> bf16 fragment-tiled [row>>4][kc][row&15][8], K=32
//   [+NW2)          W2 -> bf16 fragment-tiled [row>>4][kc][row&15][8], K=256
// Tiled layout makes each GEMM B-fragment load a contiguous 1KB wave burst
// (R9's B^T row-major gave 16 scattered 64B requests per load instr).
static constexpr int NBDEG = (EE + 255) / 256;     // 1563
static constexpr int NBMEAN = 256;
static constexpr int NBX = (NN * 4 + 255) / 256;   // 782 (thread = 8 bf16 outs)
static constexpr int NW1 = 32;
static constexpr int NW2 = 256;
__global__ void k_pre(const int* __restrict__ dst, const float* __restrict__ ea,
                      const float* __restrict__ x, const float* __restrict__ W1,
                      const float* __restrict__ W2, int* __restrict__ deg,
                      float* __restrict__ msum, unsigned short* __restrict__ xb,
                      unsigned short* __restrict__ w1t, unsigned short* __restrict__ w2t) {
  const int b = blockIdx.x;
  const int t = threadIdx.x;
  if (b < NBDEG) {
    int e = b * 256 + t;
    if (e < EE) atomicAdd(&deg[dst[e]], 1);
  } else if (b < NBDEG + NBMEAN) {
    float s[6] = {0, 0, 0, 0, 0, 0};
    for (int e = (b - NBDEG) * 256 + t; e < EE; e += NBMEAN * 256) {
#pragma unroll
      for (int d = 0; d < 6; d++) s[d] += ea[(size_t)e * 6 + d];
    }
    __shared__ float ls[6];
    if (t < 6) ls[t] = 0.f;
    __syncthreads();
#pragma unroll
    for (int d = 0; d < 6; d++) atomicAdd(&ls[d], s[d]);
    __syncthreads();
    if (t < 6) atomicAdd(&msum[t], ls[t]);
  } else if (b < NBDEG + NBMEAN + NBX) {
    int i = (b - NBDEG - NBMEAN) * 256 + t;  // i indexes 8-element chunks
    if (i < NN * 4) {
      int n = i >> 2, seg = i & 3;
      unsigned short v[8];
#pragma unroll
      for (int j = 0; j < 8; j++) {
        int k = seg * 8 + j;
        v[j] = (k < 29) ? f2bf(x[(size_t)n * 29 + k]) : (unsigned short)0;
      }
      *(short8*)(xb + (size_t)n * 32 + seg * 8) = *(short8*)v;
    }
  } else if (b < NBDEG + NBMEAN + NBX + NW1) {
    int i = (b - NBDEG - NBMEAN - NBX) * 256 + t;  // 8192 elems
    int row = i >> 5, k = i & 31;
    unsigned short v = (k < 29) ? f2bf(W1[(size_t)k * 256 + row]) : (unsigned short)0;
    w1t[((row >> 4) * 4 + (k >> 3)) * 128 + (row & 15) * 8 + (k & 7)] = v;
  } else {
    int i = (b - NBDEG - NBMEAN - NBX - NW1) * 256 + t;  // 65536 elems
    int row = i >> 8, k = i & 255;
    w2t[((row >> 4) * 32 + (k >> 3)) * 128 + (row & 15) * 8 + (k & 7)] = f2bf(W2[(size_t)k * 256 + row]);
  }
}

// block-level exclusive scan of deg -> rowptr (partial), block totals -> bsums
__global__ void k_scan1(const int* __restrict__ deg, int* __restrict__ rowptr, int* __restrict__ bsums) {
  __shared__ int sh[256];
  int i = blockIdx.x * 256 + threadIdx.x;
  int v = (i < NN) ? deg[i] : 0;
  sh[threadIdx.x] = v;
  __syncthreads();
  for (int off = 1; off < 256; off <<= 1) {
    int t = (threadIdx.x >= off) ? sh[threadIdx.x - off] : 0;
    __syncthreads();
    sh[threadIdx.x] += t;
    __syncthreads();
  }
  if (i < NN) rowptr[i] = sh[threadIdx.x] - v;  // exclusive within block
  if (threadIdx.x == 255) bsums[blockIdx.x] = sh[255];
}

// fused scan2+scan3: every block redundantly scans the 196 block sums,
// then applies its own block's exclusive prefix to rowptr.
__global__ void k_scan23(int* __restrict__ rowptr, const int* __restrict__ bsums, int nb) {
  __shared__ int sh[256];
  const int t = threadIdx.x;
  sh[t] = (t < nb) ? bsums[t] : 0;
  __syncthreads();
  for (int off = 1; off < 256; off <<= 1) {
    int tv = (t >= off) ? sh[t - off] : 0;
    __syncthreads();
    sh[t] += tv;  // inclusive scan
    __syncthreads();
  }
  const int add = (blockIdx.x == 0) ? 0 : sh[blockIdx.x - 1];
  int i = blockIdx.x * 256 + t;
  if (i < NN) rowptr[i] += add;
  if (i == 0) rowptr[NN] = EE;
}

// ---------------------------------------------------------------------------
// GEMM body (device fn): Y[M,256](bf16) = A[M,KP](bf16 row-major) @ B(tiled)
// + fused per-head logits. BM=64; 4 waves; wave w owns cols [64w,64w+64) = head w.
// B frags: contiguous 1KB wave bursts from the tiled layout. A frags: direct
// global. 2-deep register double-buffer; needs >=160 VGPRs — callers use
// __launch_bounds__(256,2) (R9's (256,3) capped VGPR at 72, pipeline deleted).
template <int KP>
__device__ __forceinline__ void gemm_body(
    int bx, const unsigned short* __restrict__ A, const unsigned short* __restrict__ Bt,
    const float* __restrict__ a_s, const float* __restrict__ a_d,
    unsigned short* __restrict__ Y, float* __restrict__ als, float* __restrict__ ald, int M) {
  const int tid = threadIdx.x;
  const int lane = tid & 63;
  const int w = tid >> 6;
  const int l15 = lane & 15;
  const int quad = lane >> 4;
  const int row0 = bx * 64;

  floatx4 acc[4][4];
#pragma unroll
  for (int i = 0; i < 4; i++)
#pragma unroll
    for (int j = 0; j < 4; j++) acc[i][j] = {0.f, 0.f, 0.f, 0.f};

  const unsigned short* pa[4];
  const unsigned short* pb[4];
#pragma unroll
  for (int i = 0; i < 4; i++) {
    int r = row0 + i * 16 + l15;
    if (r >= M) r = M - 1;  // clamp: harmless read, stores guarded below
    pa[i] = A + (size_t)r * KP + quad * 8;
  }
#pragma unroll
  for (int j = 0; j < 4; j++)
    pb[j] = Bt + (size_t)((w * 4 + j) * (KP / 8) + quad) * 128 + l15 * 8;

  constexpr int NPH = KP / 32;
  short8 af[2][4], bfr[2][4];
#pragma unroll
  for (int i = 0; i < 4; i++) af[0][i] = *(const short8*)pa[i];
#pragma unroll
  for (int j = 0; j < 4; j++) bfr[0][j] = *(const short8*)pb[j];
#pragma unroll
  for (int ph = 0; ph < NPH; ph++) {
    const int cur = ph & 1, nxt = cur ^ 1;
    if (ph + 1 < NPH) {  // prefetch next phase while this phase's MFMAs run
#pragma unroll
      for (int i = 0; i < 4; i++) {
        pa[i] += 32;
        af[nxt][i] = *(const short8*)pa[i];
      }
#pragma unroll
      for (int j = 0; j < 4; j++) {
        pb[j] += 512;  // 4 kc * 128
        bfr[nxt][j] = *(const short8*)pb[j];
      }
    }
#pragma unroll
    for (int i = 0; i < 4; i++)
#pragma unroll
      for (int j = 0; j < 4; j++)
        acc[i][j] = __builtin_amdgcn_mfma_f32_16x16x32_bf16(af[cur][i], bfr[cur][j], acc[i][j], 0, 0, 0);
  }
  // epilogue: C/D layout (m89) col = lane&15, row = (lane>>4)*4 + reg.
  float asc[4], adc[4];
#pragma unroll
  for (int j = 0; j < 4; j++) {
    asc[j] = a_s[w * 64 + j * 16 + l15];
    adc[j] = a_d[w * 64 + j * 16 + l15];
  }
#pragma unroll
  for (int i = 0; i < 4; i++) {
#pragma unroll
    for (int r = 0; r < 4; r++) {
      const int row = row0 + i * 16 + quad * 4 + r;
      unsigned ub[4];
      float hv[4];
#pragma unroll
      for (int j = 0; j < 4; j++) {
        ub[j] = f2bf(acc[i][j][r]);
        hv[j] = __uint_as_float(ub[j] << 16);  // dot uses rounded value (matches agg reads)
      }
      if (row < M) {
#pragma unroll
        for (int j = 0; j < 4; j++) Y[(size_t)row * 256 + w * 64 + j * 16 + l15] = (unsigned short)ub[j];
      }
      float ps = hv[0] * asc[0] + hv[1] * asc[1] + hv[2] * asc[2] + hv[3] * asc[3];
      float pd = hv[0] * adc[0] + hv[1] * adc[1] + hv[2] * adc[2] + hv[3] * adc[3];
#pragma unroll
      for (int off = 1; off < 16; off <<= 1) {
        ps += __shfl_xor(ps, off, 64);
        pd += __shfl_xor(pd, off, 64);
      }
      if (l15 == 0 && row < M) {
        als[row * 4 + w] = ps;
        ald[row * 4 + w] = pd;
      }
    }
  }
}

static constexpr int GB = (NN + 63) / 64;  // 782 GEMM blocks

// Fused: CSR scatter (1563 blks) ∥ per-layer params (2 blks) ∥ layer-1 GEMM (782 blks).
__global__ __launch_bounds__(256, 2) void k_scatgemm1(
    const int* __restrict__ ei, const int* __restrict__ rowptr, int* __restrict__ cursor,
    int* __restrict__ csrc, int* __restrict__ eslot, const float* __restrict__ We1,
    const float* __restrict__ ae1, const float* __restrict__ We2, const float* __restrict__ ae2,
    const float* __restrict__ msum, float* __restrict__ p1, float* __restrict__ p2,
    const unsigned short* __restrict__ xb, const unsigned short* __restrict__ w1t,
    const float* __restrict__ as1, const float* __restrict__ ad1,
    unsigned short* __restrict__ hb, float* __restrict__ als, float* __restrict__ ald) {
  const int b = blockIdx.x;
  const int t = threadIdx.x;
  if (b < NBDEG) {
    int e = b * 256 + t;
    if (e >= EE) return;
    int s = ei[e];
    int d = ei[EE + e];
    int p = atomicAdd(&cursor[d], 1);
    int slot = rowptr[d] + p;
    csrc[slot] = s;
    eslot[e] = slot;
  } else if (b < NBDEG + 2) {
    const int layer = b - NBDEG;
    const float* We = layer ? We2 : We1;
    const float* ae = layer ? ae2 : ae1;
    float* params = layer ? p2 : p1;
    __shared__ float vsh[24];
    if (t < 24) {
      int d = t >> 2, h = t & 3;
      float s = 0.f;
      for (int c = 0; c < 64; c++) s += We[d * 256 + h * 64 + c] * ae[h * 64 + c];
      vsh[t] = s;
      params[t] = s;
    }
    __syncthreads();
    if (t < 4) {
      float s = 0.f;
      const float invE = 1.0f / (float)EE;
#pragma unroll
      for (int d = 0; d < 6; d++) s += (msum[d] * invE) * vsh[d * 4 + t];
      params[24 + t] = s;
    }
  } else {
    gemm_body<32>(b - NBDEG - 2, xb, w1t, as1, ad1, hb, als, ald, NN);
  }
}

// layer-2 GEMM standalone
__global__ __launch_bounds__(256, 2) void k_gemm2(
    const unsigned short* __restrict__ A, const unsigned short* __restrict__ Bt,
    const float* __restrict__ a_s, const float* __restrict__ a_d,
    unsigned short* __restrict__ Y, float* __restrict__ als, float* __restrict__ ald) {
  gemm_body<256>(blockIdx.x, A, Bt, a_s, a_d, Y, als, ald, NN);
}

__device__ __forceinline__ float leaky02(float x) { return x > 0.f ? x : 0.2f * x; }

// per-edge exp(leaky(logit)) written in CSR slot order.
// Logits are O(1) (0.1-scaled weights) so no max-subtraction needed; exp can't overflow.
__global__ void k_edge(const int* __restrict__ ei, const float* __restrict__ ea,
                       const float* __restrict__ als, const float* __restrict__ ald,
                       const int* __restrict__ eslot, const float* __restrict__ params,
                       float* __restrict__ exa) {
  int e = blockIdx.x * blockDim.x + threadIdx.x;
  if (e >= EE) return;
  int src = ei[e], dst = ei[EE + e];
  float4 s4 = *(const float4*)(als + (size_t)src * 4);
  float4 d4 = *(const float4*)(ald + (size_t)dst * 4);
  float ed[6];
#pragma unroll
  for (int d = 0; d < 6; d++) ed[d] = ea[(size_t)e * 6 + d];
  float sl[4] = {s4.x + d4.x, s4.y + d4.y, s4.z + d4.z, s4.w + d4.w};
  float out[4];
#pragma unroll
  for (int h = 0; h < 4; h++) {
    float x = sl[h];
#pragma unroll
    for (int d = 0; d < 6; d++) x += ed[d] * params[d * 4 + h];
    out[h] = __expf(leaky02(x));
  }
  *(float4*)(exa + (size_t)eslot[e] * 4) = make_float4(out[0], out[1], out[2], out[3]);
}

// GAT aggregation on bf16 h, one wave per node, two CSR slots in flight per half
// (lanes 0-31 even slots, 32-63 odd). Software-pipelined: CSR metadata prefetched
// TWO slots ahead, the 512B h-row ONE slot ahead — each wave sustains ~4 outstanding
// row gathers so the ~700cyc L2/HBM gather latency overlaps the FMA stream
// (R10: only 2 outstanding -> fetch throughput stuck at ~2.3TB/s).
// out = (Σ ex·h[src] + ex_self·h[n]) / Σ ex, +b, relu -> bf16.
__global__ __launch_bounds__(256) void k_agg(
    const unsigned short* __restrict__ hinb, const float* __restrict__ als,
    const float* __restrict__ ald, const int* __restrict__ rowptr, const int* __restrict__ csrc,
    const float* __restrict__ exa, const float* __restrict__ params, const float* __restrict__ bias,
    unsigned short* __restrict__ houtb) {
  const int lane = threadIdx.x & 63;
  const int n = blockIdx.x * 4 + (threadIdx.x >> 6);
  if (n >= NN) return;
  const int half = lane >> 5;  // 0: even slots, 1: odd slots
  const int sl = lane & 31;    // 16B chunk (8 channels) within row
  const int head = sl >> 3;

  float acc[8];
  float ssum;
  {
    float slg = leaky02(als[n * 4 + head] + ald[n * 4 + head] + params[24 + head]);
    float exs = __expf(slg);
    float wgt = (half == 0) ? exs : 0.f;  // self term counted once (cross-half merge later)
    ssum = wgt;
    uint4 uv = *(const uint4*)(hinb + (size_t)n * 256 + sl * 8);
    acc[0] = bflo(uv.x) * wgt;
    acc[1] = bfhi(uv.x) * wgt;
    acc[2] = bflo(uv.y) * wgt;
    acc[3] = bfhi(uv.y) * wgt;
    acc[4] = bflo(uv.z) * wgt;
    acc[5] = bfhi(uv.z) * wgt;
    acc[6] = bflo(uv.w) * wgt;
    acc[7] = bfhi(uv.w) * wgt;
  }
  const int end = rowptr[n + 1];
  int s = rowptr[n] + half;
  // pipeline prologue: meta for s and s+2, row for s
  int sn1 = 0;
  float ex0 = 0.f, ex1 = 0.f;
  uint4 uv0 = make_uint4(0, 0, 0, 0);
  if (s < end) {
    int sn0 = csrc[s];
    ex0 = exa[(size_t)s * 4 + head];
    uv0 = *(const uint4*)(hinb + (size_t)sn0 * 256 + sl * 8);
  }
  if (s + 2 < end) {
    sn1 = csrc[s + 2];
    ex1 = exa[(size_t)(s + 2) * 4 + head];
  }
  while (s < end) {
    uint4 uvn = make_uint4(0, 0, 0, 0);
    int sn2 = 0;
    float ex2 = 0.f;
    if (s + 2 < end)  // prefetch next row (meta already resident)
      uvn = *(const uint4*)(hinb + (size_t)sn1 * 256 + sl * 8);
    if (s + 4 < end) {  // prefetch meta two slots ahead
      sn2 = csrc[s + 4];
      ex2 = exa[(size_t)(s + 4) * 4 + head];
    }
    acc[0] += bflo(uv0.x) * ex0;
    acc[1] += bfhi(uv0.x) * ex0;
    acc[2] += bflo(uv0.y) * ex0;
    acc[3] += bfhi(uv0.y) * ex0;
    acc[4] += bflo(uv0.z) * ex0;
    acc[5] += bfhi(uv0.z) * ex0;
    acc[6] += bflo(uv0.w) * ex0;
    acc[7] += bfhi(uv0.w) * ex0;
    ssum += ex0;
    uv0 = uvn;
    ex0 = ex1;
    sn1 = sn2;
    ex1 = ex2;
    s += 2;
  }
  // merge even/odd halves (same channel set lives at lane and lane^32)
#pragma unroll
  for (int j = 0; j < 8; j++) acc[j] += __shfl_xor(acc[j], 32, 64);
  ssum += __shfl_xor(ssum, 32, 64);
  if (half == 0) {
    const float inv = 1.f / (ssum + 1e-16f);
    float4 b0 = *(const float4*)(bias + sl * 8);
    float4 b1 = *(const float4*)(bias + sl * 8 + 4);
    const float bb[8] = {b0.x, b0.y, b0.z, b0.w, b1.x, b1.y, b1.z, b1.w};
    uint p[4];
#pragma unroll
    for (int j = 0; j < 4; j++) {
      float e0 = fmaxf(acc[2 * j] * inv + bb[2 * j], 0.f);
      float e1 = fmaxf(acc[2 * j + 1] * inv + bb[2 * j + 1], 0.f);
      p[j] = (uint)f2bf(e0) | ((uint)f2bf(e1) << 16);
    }
    *(uint4*)(houtb + (size_t)n * 256 + sl * 8) = make_uint4(p[0], p[1], p[2], p[3]);
  }
}

// per-graph mean pool (bf16 in) + readout linear (256->12).
// Node range split across both 128-lane halves (R10 idled threads 128-255).
__global__ __launch_bounds__(256) void k_pool(const unsigned short* __restrict__ hb,
                                              const int* __restrict__ batch,
                                              const float* __restrict__ Wl,
                                              const float* __restrict__ bl,
                                              float* __restrict__ out) {
  int g = blockIdx.x;
  int t = threadIdx.x;
  int lo = 0, hi = NN;
  while (lo < hi) {
    int mid = (lo + hi) >> 1;
    if (batch[mid] < g) lo = mid + 1; else hi = mid;
  }
  int start = lo;
  hi = NN;
  while (lo < hi) {
    int mid = (lo + hi) >> 1;
    if (batch[mid] < g + 1) lo = mid + 1; else hi = mid;
  }
  int end = lo;
  const int mid2 = start + ((end - start) >> 1);
  __shared__ float sp[256], sq[256];
  {
    const int c = t & 127;
    const int hseg = t >> 7;  // 0: [start,mid2), 1: [mid2,end)
    const int a = hseg ? mid2 : start;
    const int b = hseg ? end : mid2;
    float s0 = 0.f, s1 = 0.f;
    for (int n2 = a; n2 < b; n2++) {
      uint u = ((const uint*)(hb + (size_t)n2 * 256))[c];
      s0 += bflo(u);
      s1 += bfhi(u);
    }
    float* dst = hseg ? sq : sp;
    dst[2 * c] = s0;
    dst[2 * c + 1] = s1;
  }
  __syncthreads();
  if (t < TASKS) {
    float invc = 1.f / fmaxf((float)(end - start), 1.f);
    float o = bl[t];
    for (int c = 0; c < 256; c++) o += (sp[c] + sq[c]) * invc * Wl[c * 12 + t];
    out[(size_t)g * 12 + t] = o;
  }
}

// ---------------------------------------------------------------------------
extern "C" void kernel_launch(void* const* d_in, const int* in_sizes, int n_in,
                              void* d_out, int out_size, void* d_ws, size_t ws_size,
                              hipStream_t stream) {
  const float* x = (const float*)d_in[0];
  const int* ei = (const int*)d_in[1];
  const float* ea = (const float*)d_in[2];
  const int* batch = (const int*)d_in[3];
  const float* W1 = (const float*)d_in[4];
  const float* as1 = (const float*)d_in[5];
  const float* ad1 = (const float*)d_in[6];
  const float* We1 = (const float*)d_in[7];
  const float* ae1 = (const float*)d_in[8];
  const float* b1 = (const float*)d_in[9];
  const float* W2 = (const float*)d_in[10];
  const float* as2 = (const float*)d_in[11];
  const float* ad2 = (const float*)d_in[12];
  const float* We2 = (const float*)d_in[13];
  const float* ae2 = (const float*)d_in[14];
  const float* b2 = (const float*)d_in[15];
  const float* Wl = (const float*)d_in[16];
  const float* bl = (const float*)d_in[17];
  float* out = (float*)d_out;

  // workspace carve-up (256B aligned)
  char* ws = (char*)d_ws;
  size_t off = 0;
  auto take = [&](size_t bytes) -> char* {
    char* p = ws + off;
    off = (off + bytes + 255) & ~(size_t)255;
    return p;
  };
  float* msum = (float*)take(8 * 4);
  int* deg = (int*)take((size_t)NN * 4);
  int* cursor = (int*)take((size_t)NN * 4);
  size_t zero_end = off;  // msum+deg+cursor need zeroing
  int* rowptr = (int*)take((size_t)(NN + 1) * 4);
  int* bsums = (int*)take(256 * 4);
  int* csrc = (int*)take((size_t)EE * 4);
  int* eslot = (int*)take((size_t)EE * 4);
  float* exa = (float*)take((size_t)EE * 4 * 4);
  float* p1 = (float*)take(32 * 4);
  float* p2 = (float*)take(32 * 4);
  float* als = (float*)take((size_t)NN * 4 * 4);
  float* ald = (float*)take((size_t)NN * 4 * 4);
  unsigned short* hb = (unsigned short*)take((size_t)NN * 256 * 2);  // GEMM out (bf16)
  unsigned short* ab = (unsigned short*)take((size_t)NN * 256 * 2);  // agg out (bf16)
  unsigned short* xb = (unsigned short*)take((size_t)NN * 32 * 2);
  unsigned short* w1t = (unsigned short*)take((size_t)256 * 32 * 2);
  unsigned short* w2t = (unsigned short*)take((size_t)256 * 256 * 2);
  (void)ws_size;

  hipMemsetAsync(ws, 0, zero_end, stream);

  const int nbN = (NN + 255) / 256;  // 196
  const int nbE = (EE + 255) / 256;  // 1563

  k_pre<<<NBDEG + NBMEAN + NBX + NW1 + NW2, 256, 0, stream>>>(ei + EE, ea, x, W1, W2,
                                                              deg, msum, xb, w1t, w2t);
  k_scan1<<<nbN, 256, 0, stream>>>(deg, rowptr, bsums);
  k_scan23<<<nbN, 256, 0, stream>>>(rowptr, bsums, nbN);

  // scatter ∥ params ∥ layer-1 GEMM (independent partitions)
  k_scatgemm1<<<NBDEG + 2 + GB, 256, 0, stream>>>(ei, rowptr, cursor, csrc, eslot,
                                                  We1, ae1, We2, ae2, msum, p1, p2,
                                                  xb, w1t, as1, ad1, hb, als, ald);

  // Layer 1 (cont.)
  k_edge<<<nbE, 256, 0, stream>>>(ei, ea, als, ald, eslot, p1, exa);
  k_agg<<<NN / 4, 256, 0, stream>>>(hb, als, ald, rowptr, csrc, exa, p1, b1, ab);

  // Layer 2
  k_gemm2<<<GB, 256, 0, stream>>>(ab, w2t, as2, ad2, hb, als, ald);
  k_edge<<<nbE, 256, 0, stream>>>(ei, ea, als, ald, eslot, p2, exa);
  k_agg<<<NN / 4, 256, 0, stream>>>(hb, als, ald, rowptr, csrc, exa, p2, b2, ab);

  // Pool + readout
  k_pool<<<GG, 256, 0, stream>>>(ab, batch, Wl, bl, out);
}